// Round 10
// baseline (444.906 us; speedup 1.0000x reference)
//
#include <hip/hip_runtime.h>
#include <float.h>

#define NPTS 4096
#define BN   16384
#define DT   128
#define DIN  64

typedef short v8s __attribute__((ext_vector_type(8)));
typedef float v4f __attribute__((ext_vector_type(4)));

__device__ __forceinline__ unsigned short f2bf(float f) {
    union { float f; unsigned u; } v; v.f = f;
    unsigned r = v.u + 0x7fff + ((v.u >> 16) & 1);
    return (unsigned short)(r >> 16);
}
__device__ __forceinline__ float bf2f(unsigned short s) {
    union { unsigned u; float f; } v; v.u = ((unsigned)s) << 16;
    return v.f;
}
// packed RNE f32x2 -> bf16x2 in ONE instruction
__device__ __forceinline__ unsigned pack2(float lo, float hi) {
    unsigned r;
    asm("v_cvt_pk_bf16_f32 %0, %1, %2" : "=v"(r) : "v"(lo), "v"(hi));
    return r;
}

#define CSW(da,ia,db,ib) { bool sw_ = (da>db)||((da==db)&&(ia>ib)); \
    float td_=sw_?db:da, tD_=sw_?da:db; int ti_=sw_?ib:ia, tI_=sw_?ia:ib; \
    da=td_; db=tD_; ia=ti_; ib=tI_; }

// ------------------------------------------------------------------ fp
// feat + prep merged (both input-only): [0,1024) feat, [1024,1280) prep.
// Runs FIRST so knn can read the prep-built pos4 (L2-resident float4).
__global__ __launch_bounds__(256) void fp_kernel(
    const float* __restrict__ pos, const float* __restrict__ x,
    const float* __restrict__ fc1w, const float* __restrict__ fc1b,
    const float* __restrict__ wq, const float* __restrict__ wk,
    const float* __restrict__ wv,
    const float* __restrict__ d2w, const float* __restrict__ g1w,
    const float* __restrict__ g2w,
    float4* __restrict__ pos4, unsigned short* __restrict__ wB,
    unsigned short* __restrict__ qb, unsigned short* __restrict__ kb,
    unsigned short* __restrict__ vb) {
    __shared__ float smem[3072];   // 12 KB (feat role)
    int bid = blockIdx.x;
    int t = threadIdx.x;

    if (bid < 1024) {
        // ======================= feat role =================================
        float (*xs)[64]  = (float(*)[64])smem;            // 4 KB
        float (*hs)[128] = (float(*)[128])(smem + 1024);  // 8 KB
        int rb = bid * 16;

        for (int i = t; i < 16*64; i += 256) xs[i>>6][i&63] = x[rb*64 + i];
        __syncthreads();

        int f4 = (t & 31) * 4;
        int r0 = (t >> 5) * 2, r1 = r0 + 1;
        float a0[4], a1[4];
#pragma unroll
        for (int jf = 0; jf < 4; jf++) { a0[jf] = fc1b[f4+jf]; a1[jf] = fc1b[f4+jf]; }
#pragma unroll 4
        for (int c = 0; c < 64; c += 4) {
            float s0[4], s1[4];
            *(float4*)s0 = *(const float4*)&xs[r0][c];
            *(float4*)s1 = *(const float4*)&xs[r1][c];
#pragma unroll
            for (int jc = 0; jc < 4; jc++) {
                float w[4];
                *(float4*)w = *(const float4*)&fc1w[(c+jc)*128 + f4];
#pragma unroll
                for (int jf = 0; jf < 4; jf++) {
                    a0[jf] = fmaf(s0[jc], w[jf], a0[jf]);
                    a1[jf] = fmaf(s1[jc], w[jf], a1[jf]);
                }
            }
        }
        *(float4*)&hs[r0][f4] = *(float4*)a0;
        *(float4*)&hs[r1][f4] = *(float4*)a1;
        __syncthreads();

        const float* Ws[3] = { wq, wk, wv };
        unsigned short* Os[3] = { qb, kb, vb };
        for (int mtx = 0; mtx < 3; mtx++) {
            const float* __restrict__ W = Ws[mtx];
#pragma unroll
            for (int jf = 0; jf < 4; jf++) { a0[jf] = 0.f; a1[jf] = 0.f; }
#pragma unroll 4
            for (int c = 0; c < 128; c += 4) {
                float s0[4], s1[4];
                *(float4*)s0 = *(const float4*)&hs[r0][c];
                *(float4*)s1 = *(const float4*)&hs[r1][c];
#pragma unroll
                for (int jc = 0; jc < 4; jc++) {
                    float w[4];
                    *(float4*)w = *(const float4*)&W[(c+jc)*128 + f4];
#pragma unroll
                    for (int jf = 0; jf < 4; jf++) {
                        a0[jf] = fmaf(s0[jc], w[jf], a0[jf]);
                        a1[jf] = fmaf(s1[jc], w[jf], a1[jf]);
                    }
                }
            }
            unsigned short* O = Os[mtx];
            uint2 s0v, s1v;
            s0v.x = pack2(a0[0], a0[1]); s0v.y = pack2(a0[2], a0[3]);
            s1v.x = pack2(a1[0], a1[1]); s1v.y = pack2(a1[2], a1[3]);
            *(uint2*)&O[(size_t)(rb+r0)*128 + f4] = s0v;
            *(uint2*)&O[(size_t)(rb+r1)*128 + f4] = s1v;
        }
    } else {
        // ======================= prep role =================================
        int i = (bid - 1024) * 256 + t;
        if (i < BN) {
            float p0 = pos[i*3], p1 = pos[i*3+1], p2 = pos[i*3+2];
            pos4[i] = make_float4(p0, p1, p2, fmaf(p2, p2, fmaf(p1, p1, p0*p0)));
        } else {
            int e = i - BN; int m = e >> 14; e &= 16383;
            int k = e >> 7, n = e & 127;
            const float* W = (m == 0) ? d2w : (m == 1) ? g1w : g2w;
            float val = W[k*128 + n];
            int tile = n >> 4, nl = n & 15, ks = k >> 5, q = (k >> 3) & 3, j = k & 7;
            wB[m*16384 + ((tile*4 + ks)*64 + q*16 + nl)*8 + j] = f2bf(val);
        }
    }
}

// ------------------------------------------------------------------ knn
// r8 version: pos4 from global L2 + 16 KB LDS -> 16 waves/CU, 4x unrolled
// scans (4 independent dwordx4 loads in flight per wave per iteration).
__global__ __launch_bounds__(256, 4) void knn_kernel(const float4* __restrict__ pos4,
                                                     int* __restrict__ knnb) {
    __shared__ float scd[8][256];   // 8 KB
    __shared__ int   sci[8][256];   // 8 KB
    int t = threadIdx.x, lane = t & 63, w = t >> 6;
    int n0 = blockIdx.x * 8 + w * 2;
    int base = n0 & ~(NPTS - 1);
    float4 pa = pos4[n0], pb = pos4[n0 + 1];

    float mina = FLT_MAX, minb = FLT_MAX;
    for (int m = lane; m < NPTS; m += 256) {
        float4 c0 = pos4[base + m];
        float4 c1 = pos4[base + m + 64];
        float4 c2 = pos4[base + m + 128];
        float4 c3 = pos4[base + m + 192];
        float da0 = (pa.w + c0.w) - 2.0f * fmaf(pa.z, c0.z, fmaf(pa.y, c0.y, pa.x*c0.x));
        float db0 = (pb.w + c0.w) - 2.0f * fmaf(pb.z, c0.z, fmaf(pb.y, c0.y, pb.x*c0.x));
        float da1 = (pa.w + c1.w) - 2.0f * fmaf(pa.z, c1.z, fmaf(pa.y, c1.y, pa.x*c1.x));
        float db1 = (pb.w + c1.w) - 2.0f * fmaf(pb.z, c1.z, fmaf(pb.y, c1.y, pb.x*c1.x));
        float da2 = (pa.w + c2.w) - 2.0f * fmaf(pa.z, c2.z, fmaf(pa.y, c2.y, pa.x*c2.x));
        float db2 = (pb.w + c2.w) - 2.0f * fmaf(pb.z, c2.z, fmaf(pb.y, c2.y, pb.x*c2.x));
        float da3 = (pa.w + c3.w) - 2.0f * fmaf(pa.z, c3.z, fmaf(pa.y, c3.y, pa.x*c3.x));
        float db3 = (pb.w + c3.w) - 2.0f * fmaf(pb.z, c3.z, fmaf(pb.y, c3.y, pb.x*c3.x));
        mina = fminf(mina, fminf(fminf(da0, da1), fminf(da2, da3)));
        minb = fminf(minb, fminf(fminf(db0, db1), fminf(db2, db3)));
    }
    // tau = 16th smallest of the 64 lane-minima via bitonic sort
    float taua, taub;
    {
        float va = mina, vb_ = minb;
#pragma unroll
        for (int k = 2; k <= 64; k <<= 1) {
#pragma unroll
            for (int j = k >> 1; j > 0; j >>= 1) {
                float oa = __shfl_xor(va, j, 64);
                float ob = __shfl_xor(vb_, j, 64);
                bool low = (lane & j) == 0;
                bool asc = (lane & k) == 0;
                va  = (low == asc) ? fminf(va, oa)  : fmaxf(va, oa);
                vb_ = (low == asc) ? fminf(vb_, ob) : fmaxf(vb_, ob);
            }
        }
        taua = __shfl(va, 15, 64);
        taub = __shfl(vb_, 15, 64);
    }
    int ca = 0, cb = 0;
    for (int m = lane; m < NPTS; m += 256) {
        float4 cc[4];
        cc[0] = pos4[base + m];
        cc[1] = pos4[base + m + 64];
        cc[2] = pos4[base + m + 128];
        cc[3] = pos4[base + m + 192];
#pragma unroll
        for (int u = 0; u < 4; u++) {
            float4 c = cc[u];
            int mm = m + u*64;
            float da = (pa.w + c.w) - 2.0f * fmaf(pa.z, c.z, fmaf(pa.y, c.y, pa.x*c.x));
            float db = (pb.w + c.w) - 2.0f * fmaf(pb.z, c.z, fmaf(pb.y, c.y, pb.x*c.x));
            bool ta = da <= taua, tb_ = db <= taub;
            unsigned long long ma = __ballot(ta), mb = __ballot(tb_);
            unsigned long long lower = (1ull << lane) - 1ull;
            if (ta) {
                int p_ = ca + __popcll(ma & lower);
                if (p_ < 256) { scd[w*2][p_] = da; sci[w*2][p_] = base + mm; }
            }
            if (tb_) {
                int p_ = cb + __popcll(mb & lower);
                if (p_ < 256) { scd[w*2+1][p_] = db; sci[w*2+1][p_] = base + mm; }
            }
            ca += __popcll(ma); cb += __popcll(mb);
        }
    }
    if (ca > 256) ca = 256;
    if (cb > 256) cb = 256;
    for (int i = ca + lane; i < 256; i += 64) { scd[w*2][i]   = FLT_MAX; sci[w*2][i]   = 0x7fffffff; }
    for (int i = cb + lane; i < 256; i += 64) { scd[w*2+1][i] = FLT_MAX; sci[w*2+1][i] = 0x7fffffff; }

    for (int pt = 0; pt < 2; pt++) {
        int s = w*2 + pt;
        float4 dv = *(const float4*)&scd[s][lane*4];
        int4   iv = *(const int4*)&sci[s][lane*4];
        CSW(dv.x, iv.x, dv.y, iv.y);
        CSW(dv.z, iv.z, dv.w, iv.w);
        CSW(dv.x, iv.x, dv.z, iv.z);
        CSW(dv.y, iv.y, dv.w, iv.w);
        CSW(dv.y, iv.y, dv.z, iv.z);
        int p = 0, myres = 0;
        for (int r = 0; r < 16; r++) {
            float hd = p==0 ? dv.x : p==1 ? dv.y : p==2 ? dv.z : p==3 ? dv.w : FLT_MAX;
            int   hi = p==0 ? iv.x : p==1 ? iv.y : p==2 ? iv.z : p==3 ? iv.w : 0x7fffffff;
            float bd = hd; int bi = hi;
            for (int off = 32; off; off >>= 1) {
                float od = __shfl_xor(bd, off, 64);
                int   oi = __shfl_xor(bi, off, 64);
                if (od < bd || (od == bd && oi < bi)) { bd = od; bi = oi; }
            }
            if (hi == bi) p++;
            if (lane == r) myres = bi;
        }
        if (lane < 16) knnb[(n0 + pt)*16 + lane] = myres;
    }
}

// ------------------------------------------------------------------ fused
// r8 structure + attribute form (fastest measured), with stage-3 register
// diet: av[8][4] (32 VGPR) replaced by vP[16] (v preloaded bf16-packed like
// peP) -- the tile is then free during the softmax loop, so attn values
// stream straight to LDS and flush per half.  Net -16 VGPR ~= the measured
// ~13-dword spill at the 1024-thread 128-reg budget (r9 postmortem).
__global__ __attribute__((amdgpu_waves_per_eu(4, 4)))
__launch_bounds__(1024) void fused_kernel(
    const float4* __restrict__ pos4, const int* __restrict__ knnb,
    const unsigned short* __restrict__ qb, const unsigned short* __restrict__ kb,
    const unsigned short* __restrict__ vb,
    const unsigned short* __restrict__ wB,
    const float* __restrict__ d1w, const float* __restrict__ d1b,
    const float* __restrict__ d2b, const float* __restrict__ g1b,
    const float* __restrict__ g2b,
    float* __restrict__ res, float* __restrict__ attn) {
    __shared__ unsigned short ws_[49152];   // 96 KB: d2 | g1 | g2 B-frags
    __shared__ unsigned short tb[16][2048]; // 4 KB/wave tile (64 KB)
    int t = threadIdx.x;
    int lane = t & 63, w = t >> 6;
    int col = lane & 15, quad = lane >> 4;
    const float inv_s = 0.08838834764831845f;   // 1/sqrt(128)

    unsigned short* tw = &tb[w][0];
    float* twf = (float*)tw;                    // tile viewed as f32 [16][64]

    // ---- load all three weight matrices, once
    {
        const uint4* src = (const uint4*)wB;
        uint4* dst = (uint4*)ws_;
        for (int i = t; i < 6144; i += 1024) dst[i] = src[i];
    }
    __syncthreads();   // the only barrier

#pragma unroll
    for (int it = 0; it < 2; it++) {
        int n = (blockIdx.x * 16 + w) * 2 + it;
        {
            int jid = knnb[n*16 + col];

            // ---- wide-gather k rows -> tile (swizzled 8-elem groups)
#pragma unroll
            for (int g = 0; g < 4; g++) {
                int kk2 = quad*4 + g;
                int jr2 = __shfl(jid, kk2);
                v8s kr = *(const v8s*)&kb[(size_t)jr2*128 + col*8];
                *(v8s*)&tw[kk2*128 + ((col ^ (kk2 & 7)) << 3)] = kr;
            }

            float4 pn = pos4[n];
            float4 pj = pos4[jid];
            float dx = pn.x - pj.x, dy = pn.y - pj.y, dz = pn.z - pj.z;

            // hd in A-frag layout (cvt_pk packs pairs)
            v8s af[4];
#pragma unroll
            for (int ks = 0; ks < 4; ks++) {
                int fb = ks*32 + quad*8;
                float w0[8], w1[8], w2[8], bb[8];
                *(float4*)&w0[0] = *(const float4*)&d1w[fb];
                *(float4*)&w0[4] = *(const float4*)&d1w[fb+4];
                *(float4*)&w1[0] = *(const float4*)&d1w[128+fb];
                *(float4*)&w1[4] = *(const float4*)&d1w[128+fb+4];
                *(float4*)&w2[0] = *(const float4*)&d1w[256+fb];
                *(float4*)&w2[4] = *(const float4*)&d1w[256+fb+4];
                *(float4*)&bb[0] = *(const float4*)&d1b[fb];
                *(float4*)&bb[4] = *(const float4*)&d1b[fb+4];
                union { v8s s; unsigned u[4]; } afu;
#pragma unroll
                for (int j2 = 0; j2 < 4; j2++) {
                    float h0 = fmaf(dz, w2[j2*2],   fmaf(dy, w1[j2*2],   fmaf(dx, w0[j2*2],   bb[j2*2])));
                    float h1 = fmaf(dz, w2[j2*2+1], fmaf(dy, w1[j2*2+1], fmaf(dx, w0[j2*2+1], bb[j2*2+1])));
                    afu.u[j2] = pack2(fmaxf(h0, 0.0f), fmaxf(h1, 0.0f));
                }
                af[ks] = afu.s;
            }

            v8s frag[4];
            unsigned peP[16];

            // ===== stage 1: pe = hd@d2; a = q - k + pe -> tile -> frag =====
            {
                unsigned wo = 0; asm volatile("" : "+v"(wo));
#pragma unroll
                for (int tt = 0; tt < 8; tt++) {
                    v4f acc = {0.f, 0.f, 0.f, 0.f};
#pragma unroll
                    for (int ks = 0; ks < 4; ks++) {
                        v8s b = *(const v8s*)&ws_[wo + ((tt*4 + ks) << 9) + (lane << 3)];
                        acc = __builtin_amdgcn_mfma_f32_16x16x32_bf16(af[ks], b, acc, 0, 0, 0);
                    }
                    int cg = tt*16 + col;
                    float bias = d2b[cg];
                    float qv = bf2f(qb[(size_t)n*128 + cg]);
                    float pe0 = 0.f, pe1 = 0.f;
#pragma unroll
                    for (int r = 0; r < 4; r++) {
                        int kk = quad*4 + r;
                        int pidx = kk*128 + ((((cg >> 3) ^ (kk & 7))) << 3) + (cg & 6);
                        unsigned kp = *(const unsigned*)&tw[pidx];
                        float kv = bf2f((unsigned short)((lane & 1) ? (kp >> 16) : (kp & 0xffff)));
                        float pe = acc[r] + bias;
                        if (r == 0) pe0 = pe;
                        if (r == 1) { peP[tt*2]   = pack2(pe0, pe); }
                        if (r == 2) pe1 = pe;
                        if (r == 3) { peP[tt*2+1] = pack2(pe1, pe); }
                        float a  = qv - kv + pe;
                        float o = __shfl_xor(a, 1);
                        if ((lane & 1) == 0) *(unsigned*)&tw[pidx] = pack2(a, o);
                    }
                }
#pragma unroll
                for (int ks = 0; ks < 4; ks++)
                    frag[ks] = *(const v8s*)&tw[col*128 + ((((ks*4 + quad) ^ (col & 7))) << 3)];
            }

            // ===== stage 2: gh = relu(a @ g1) -> tile -> frag ==============
            {
                unsigned wo = 16384; asm volatile("" : "+v"(wo));
#pragma unroll
                for (int tt = 0; tt < 8; tt++) {
                    v4f acc = {0.f, 0.f, 0.f, 0.f};
#pragma unroll
                    for (int ks = 0; ks < 4; ks++) {
                        v8s b = *(const v8s*)&ws_[wo + ((tt*4 + ks) << 9) + (lane << 3)];
                        acc = __builtin_amdgcn_mfma_f32_16x16x32_bf16(frag[ks], b, acc, 0, 0, 0);
                    }
                    float bias = g1b[tt*16 + col];
#pragma unroll
                    for (int r = 0; r < 4; r++) {
                        float h = fmaxf(acc[r] + bias, 0.0f);
                        float o = __shfl_xor(h, 1);
                        if ((lane & 1) == 0) {
                            int kk = quad*4 + r;
                            int cg = tt*16 + col;
                            int idx = kk*128 + ((((cg >> 3) ^ (kk & 7))) << 3) + (cg & 7);
                            *(unsigned*)&tw[idx] = pack2(h, o);
                        }
                    }
                }
#pragma unroll
                for (int ks = 0; ks < 4; ks++)
                    frag[ks] = *(const v8s*)&tw[col*128 + ((((ks*4 + quad) ^ (col & 7))) << 3)];
            }

            // ===== stage 3: gm = gh@g2 -> softmax -> attn, res =============
            {
                // gather v rows -> tile (gh already consumed into frag)
#pragma unroll
                for (int g = 0; g < 4; g++) {
                    int kk2 = quad*4 + g;
                    int jr2 = __shfl(jid, kk2);
                    v8s vr = *(const v8s*)&vb[(size_t)jr2*128 + col*8];
                    *(v8s*)&tw[kk2*128 + ((col ^ (kk2 & 7)) << 3)] = vr;
                }

                // preload v into bf16-packed regs (peP layout) -- frees the
                // tile so attn streams to LDS in-loop (no av[8][4] buffer)
                unsigned vP[16];
#pragma unroll
                for (int tt = 0; tt < 8; tt++) {
                    int cg = tt*16 + col;
#pragma unroll
                    for (int rp2 = 0; rp2 < 2; rp2++) {
                        int kk0 = quad*4 + rp2*2;
                        int kk1 = kk0 + 1;
                        int pidx0 = kk0*128 + ((((cg >> 3) ^ (kk0 & 7))) << 3) + (cg & 6);
                        int pidx1 = kk1*128 + ((((cg >> 3) ^ (kk1 & 7))) << 3) + (cg & 6);
                        unsigned v0 = *(const unsigned*)&tw[pidx0];
                        unsigned v1 = *(const unsigned*)&tw[pidx1];
                        unsigned lo = (lane & 1) ? (v0 >> 16) : (v0 & 0xffffu);
                        unsigned hi = (lane & 1) ? (v1 & 0xffff0000u) : (v1 << 16);
                        vP[tt*2 + rp2] = lo | hi;
                    }
                }

                unsigned wo = 32768; asm volatile("" : "+v"(wo));
#pragma unroll
                for (int h = 0; h < 2; h++) {
#pragma unroll
                    for (int tt2 = 0; tt2 < 4; tt2++) {
                        int tt = h*4 + tt2;
                        v4f acc = {0.f, 0.f, 0.f, 0.f};
#pragma unroll
                        for (int ks = 0; ks < 4; ks++) {
                            v8s b = *(const v8s*)&ws_[wo + ((tt*4 + ks) << 9) + (lane << 3)];
                            acc = __builtin_amdgcn_mfma_f32_16x16x32_bf16(frag[ks], b, acc, 0, 0, 0);
                        }
                        int cg = tt*16 + col;
                        float bias = g2b[cg];
                        float l[4];
                        float mx = -FLT_MAX;
#pragma unroll
                        for (int r = 0; r < 4; r++) {
                            l[r] = (acc[r] + bias) * inv_s;
                            mx = fmaxf(mx, l[r]);
                        }
                        mx = fmaxf(mx, __shfl_xor(mx, 16));
                        mx = fmaxf(mx, __shfl_xor(mx, 32));
                        float s = 0.f;
#pragma unroll
                        for (int r = 0; r < 4; r++) { l[r] = __expf(l[r] - mx); s += l[r]; }
                        s += __shfl_xor(s, 16);
                        s += __shfl_xor(s, 32);
                        float rs = 1.0f / s;
                        float rp = 0.f;
#pragma unroll
                        for (int r = 0; r < 4; r++) {
                            int kk = quad*4 + r;
                            unsigned vpk = vP[tt*2 + (r >> 1)];
                            float vv = bf2f((unsigned short)((r & 1) ? (vpk >> 16) : (vpk & 0xffff)));
                            unsigned pp = peP[tt*2 + (r >> 1)];
                            float pe = bf2f((unsigned short)((r & 1) ? (pp >> 16) : (pp & 0xffff)));
                            float a_ = l[r] * rs;
                            twf[kk*64 + ((tt2*16 + col) ^ ((kk & 4) << 2))] = a_;
                            rp = fmaf(a_, vv + pe, rp);
                        }
                        rp += __shfl_xor(rp, 16);
                        rp += __shfl_xor(rp, 32);
                        if (lane < 16) res[(size_t)n*128 + cg] = rp;
                    }
                    // flush staged half: 4x (ds_read_b128 + 256B dwordx4)
#pragma unroll
                    for (int s4 = 0; s4 < 4; s4++) {
                        int kk = s4*4 + quad;
                        int c4 = col*4;
                        float4 a4 = *(const float4*)&twf[kk*64 + (c4 ^ ((kk & 4) << 2))];
                        *(float4*)&attn[(size_t)(n*16 + kk)*128 + h*64 + c4] = a4;
                    }
                }
            }
        }
    }
}

// ------------------------------------------------------------------ epi
__global__ __launch_bounds__(256) void epi_kernel(
    const float* __restrict__ res, const float* __restrict__ fc2w,
    const float* __restrict__ fc2b, const float* __restrict__ x,
    float* __restrict__ out) {
    __shared__ float fw[128][64];   // 32 KB
    __shared__ float rs[16][128];   // 8 KB
    int t = threadIdx.x;
    int rb = blockIdx.x * 16;
    for (int i = t; i < 8192; i += 256) fw[i >> 6][i & 63] = fc2w[i];
    for (int i = t; i < 2048; i += 256) rs[i >> 7][i & 127] = res[(size_t)rb*128 + i];
    __syncthreads();

    int o = t & 63, g = t >> 6;
#pragma unroll
    for (int rr = 0; rr < 4; rr++) {
        int lr = rr*4 + g;
        int n = rb + lr;
        float a0 = 0.f, a1 = 0.f, a2 = 0.f, a3 = 0.f;
#pragma unroll 8
        for (int c = 0; c < 128; c += 4) {
            a0 = fmaf(rs[lr][c],   fw[c][o],   a0);
            a1 = fmaf(rs[lr][c+1], fw[c+1][o], a1);
            a2 = fmaf(rs[lr][c+2], fw[c+2][o], a2);
            a3 = fmaf(rs[lr][c+3], fw[c+3][o], a3);
        }
        out[(size_t)n*64 + o] = (a0 + a1) + (a2 + a3) + fc2b[o] + x[(size_t)n*64 + o];
    }
}

// ------------------------------------------------------------------ launch
extern "C" void kernel_launch(void* const* d_in, const int* in_sizes, int n_in,
                              void* d_out, int out_size, void* d_ws, size_t ws_size,
                              hipStream_t stream) {
    (void)in_sizes; (void)n_in; (void)out_size; (void)ws_size;
    const float* x    = (const float*)d_in[0];
    const float* pos  = (const float*)d_in[1];
    const float* fc1w = (const float*)d_in[2];
    const float* fc1b = (const float*)d_in[3];
    const float* fc2w = (const float*)d_in[4];
    const float* fc2b = (const float*)d_in[5];
    const float* d1w  = (const float*)d_in[6];
    const float* d1b  = (const float*)d_in[7];
    const float* d2w  = (const float*)d_in[8];
    const float* d2b  = (const float*)d_in[9];
    const float* g1w  = (const float*)d_in[10];
    const float* g1b  = (const float*)d_in[11];
    const float* g2w  = (const float*)d_in[12];
    const float* g2b  = (const float*)d_in[13];
    const float* wq   = (const float*)d_in[14];
    const float* wk   = (const float*)d_in[15];
    const float* wv   = (const float*)d_in[16];

    float* out      = (float*)d_out;
    float* attn_out = out + (size_t)BN * DIN;

    char* W = (char*)d_ws;
    float4*         pos4  = (float4*)(W + 0);                 // 256 KB
    unsigned short* wB    = (unsigned short*)(W + 262144);    // 96 KB
    int*            knnb  = (int*)(W + 376832);               // 1 MB
    unsigned short* qb    = (unsigned short*)(W + 1441792);   // 4 MB
    unsigned short* kb    = (unsigned short*)(W + 5636096);   // 4 MB
    unsigned short* vb    = (unsigned short*)(W + 9830400);   // 4 MB
    float*          res   = (float*)(W + 14024704);           // 8 MB

    fp_kernel<<<1280, 256, 0, stream>>>(pos, x, fc1w, fc1b, wq, wk, wv,
                                        d2w, g1w, g2w, pos4, wB, qb, kb, vb);
    knn_kernel<<<2048, 256, 0, stream>>>(pos4, knnb);
    fused_kernel<<<512, 1024, 0, stream>>>(pos4, knnb, qb, kb, vb, wB, d1w, d1b,
                                           d2b, g1b, g2b, res, attn_out);
    epi_kernel<<<1024, 256, 0, stream>>>(res, fc2w, fc2b, x, out);
}

// Round 11
// 397.625 us; speedup vs baseline: 1.1189x; 1.1189x over previous
//
#include <hip/hip_runtime.h>
#include <float.h>

#define NPTS 4096
#define BN   16384
#define DT   128
#define DIN  64

typedef short v8s __attribute__((ext_vector_type(8)));
typedef float v4f __attribute__((ext_vector_type(4)));

__device__ __forceinline__ unsigned short f2bf(float f) {
    union { float f; unsigned u; } v; v.f = f;
    unsigned r = v.u + 0x7fff + ((v.u >> 16) & 1);
    return (unsigned short)(r >> 16);
}
__device__ __forceinline__ float bf2f(unsigned short s) {
    union { unsigned u; float f; } v; v.u = ((unsigned)s) << 16;
    return v.f;
}
// packed RNE f32x2 -> bf16x2 in ONE instruction
__device__ __forceinline__ unsigned pack2(float lo, float hi) {
    unsigned r;
    asm("v_cvt_pk_bf16_f32 %0, %1, %2" : "=v"(r) : "v"(lo), "v"(hi));
    return r;
}

#define CSW(da,ia,db,ib) { bool sw_ = (da>db)||((da==db)&&(ia>ib)); \
    float td_=sw_?db:da, tD_=sw_?da:db; int ti_=sw_?ib:ia, tI_=sw_?ia:ib; \
    da=td_; db=tD_; ia=ti_; ib=tI_; }

// ------------------------------------------------------------------ fp
// feat + prep merged (both input-only): [0,1024) feat, [1024,1280) prep.
// Runs FIRST so knn can read the prep-built pos4 (L2-resident float4).
__global__ __launch_bounds__(256) void fp_kernel(
    const float* __restrict__ pos, const float* __restrict__ x,
    const float* __restrict__ fc1w, const float* __restrict__ fc1b,
    const float* __restrict__ wq, const float* __restrict__ wk,
    const float* __restrict__ wv,
    const float* __restrict__ d2w, const float* __restrict__ g1w,
    const float* __restrict__ g2w,
    float4* __restrict__ pos4, unsigned short* __restrict__ wB,
    unsigned short* __restrict__ qb, unsigned short* __restrict__ kb,
    unsigned short* __restrict__ vb) {
    __shared__ float smem[3072];   // 12 KB (feat role)
    int bid = blockIdx.x;
    int t = threadIdx.x;

    if (bid < 1024) {
        // ======================= feat role =================================
        float (*xs)[64]  = (float(*)[64])smem;            // 4 KB
        float (*hs)[128] = (float(*)[128])(smem + 1024);  // 8 KB
        int rb = bid * 16;

        for (int i = t; i < 16*64; i += 256) xs[i>>6][i&63] = x[rb*64 + i];
        __syncthreads();

        int f4 = (t & 31) * 4;
        int r0 = (t >> 5) * 2, r1 = r0 + 1;
        float a0[4], a1[4];
#pragma unroll
        for (int jf = 0; jf < 4; jf++) { a0[jf] = fc1b[f4+jf]; a1[jf] = fc1b[f4+jf]; }
#pragma unroll 4
        for (int c = 0; c < 64; c += 4) {
            float s0[4], s1[4];
            *(float4*)s0 = *(const float4*)&xs[r0][c];
            *(float4*)s1 = *(const float4*)&xs[r1][c];
#pragma unroll
            for (int jc = 0; jc < 4; jc++) {
                float w[4];
                *(float4*)w = *(const float4*)&fc1w[(c+jc)*128 + f4];
#pragma unroll
                for (int jf = 0; jf < 4; jf++) {
                    a0[jf] = fmaf(s0[jc], w[jf], a0[jf]);
                    a1[jf] = fmaf(s1[jc], w[jf], a1[jf]);
                }
            }
        }
        *(float4*)&hs[r0][f4] = *(float4*)a0;
        *(float4*)&hs[r1][f4] = *(float4*)a1;
        __syncthreads();

        const float* Ws[3] = { wq, wk, wv };
        unsigned short* Os[3] = { qb, kb, vb };
        for (int mtx = 0; mtx < 3; mtx++) {
            const float* __restrict__ W = Ws[mtx];
#pragma unroll
            for (int jf = 0; jf < 4; jf++) { a0[jf] = 0.f; a1[jf] = 0.f; }
#pragma unroll 4
            for (int c = 0; c < 128; c += 4) {
                float s0[4], s1[4];
                *(float4*)s0 = *(const float4*)&hs[r0][c];
                *(float4*)s1 = *(const float4*)&hs[r1][c];
#pragma unroll
                for (int jc = 0; jc < 4; jc++) {
                    float w[4];
                    *(float4*)w = *(const float4*)&W[(c+jc)*128 + f4];
#pragma unroll
                    for (int jf = 0; jf < 4; jf++) {
                        a0[jf] = fmaf(s0[jc], w[jf], a0[jf]);
                        a1[jf] = fmaf(s1[jc], w[jf], a1[jf]);
                    }
                }
            }
            unsigned short* O = Os[mtx];
            uint2 s0v, s1v;
            s0v.x = pack2(a0[0], a0[1]); s0v.y = pack2(a0[2], a0[3]);
            s1v.x = pack2(a1[0], a1[1]); s1v.y = pack2(a1[2], a1[3]);
            *(uint2*)&O[(size_t)(rb+r0)*128 + f4] = s0v;
            *(uint2*)&O[(size_t)(rb+r1)*128 + f4] = s1v;
        }
    } else {
        // ======================= prep role =================================
        int i = (bid - 1024) * 256 + t;
        if (i < BN) {
            float p0 = pos[i*3], p1 = pos[i*3+1], p2 = pos[i*3+2];
            pos4[i] = make_float4(p0, p1, p2, fmaf(p2, p2, fmaf(p1, p1, p0*p0)));
        } else {
            int e = i - BN; int m = e >> 14; e &= 16383;
            int k = e >> 7, n = e & 127;
            const float* W = (m == 0) ? d2w : (m == 1) ? g1w : g2w;
            float val = W[k*128 + n];
            int tile = n >> 4, nl = n & 15, ks = k >> 5, q = (k >> 3) & 3, j = k & 7;
            wB[m*16384 + ((tile*4 + ks)*64 + q*16 + nl)*8 + j] = f2bf(val);
        }
    }
}

// ------------------------------------------------------------------ knn
// r8 version: pos4 from global L2 + 16 KB LDS -> 16 waves/CU, 4x unrolled
// scans (4 independent dwordx4 loads in flight per wave per iteration).
__global__ __launch_bounds__(256, 4) void knn_kernel(const float4* __restrict__ pos4,
                                                     int* __restrict__ knnb) {
    __shared__ float scd[8][256];   // 8 KB
    __shared__ int   sci[8][256];   // 8 KB
    int t = threadIdx.x, lane = t & 63, w = t >> 6;
    int n0 = blockIdx.x * 8 + w * 2;
    int base = n0 & ~(NPTS - 1);
    float4 pa = pos4[n0], pb = pos4[n0 + 1];

    float mina = FLT_MAX, minb = FLT_MAX;
    for (int m = lane; m < NPTS; m += 256) {
        float4 c0 = pos4[base + m];
        float4 c1 = pos4[base + m + 64];
        float4 c2 = pos4[base + m + 128];
        float4 c3 = pos4[base + m + 192];
        float da0 = (pa.w + c0.w) - 2.0f * fmaf(pa.z, c0.z, fmaf(pa.y, c0.y, pa.x*c0.x));
        float db0 = (pb.w + c0.w) - 2.0f * fmaf(pb.z, c0.z, fmaf(pb.y, c0.y, pb.x*c0.x));
        float da1 = (pa.w + c1.w) - 2.0f * fmaf(pa.z, c1.z, fmaf(pa.y, c1.y, pa.x*c1.x));
        float db1 = (pb.w + c1.w) - 2.0f * fmaf(pb.z, c1.z, fmaf(pb.y, c1.y, pb.x*c1.x));
        float da2 = (pa.w + c2.w) - 2.0f * fmaf(pa.z, c2.z, fmaf(pa.y, c2.y, pa.x*c2.x));
        float db2 = (pb.w + c2.w) - 2.0f * fmaf(pb.z, c2.z, fmaf(pb.y, c2.y, pb.x*c2.x));
        float da3 = (pa.w + c3.w) - 2.0f * fmaf(pa.z, c3.z, fmaf(pa.y, c3.y, pa.x*c3.x));
        float db3 = (pb.w + c3.w) - 2.0f * fmaf(pb.z, c3.z, fmaf(pb.y, c3.y, pb.x*c3.x));
        mina = fminf(mina, fminf(fminf(da0, da1), fminf(da2, da3)));
        minb = fminf(minb, fminf(fminf(db0, db1), fminf(db2, db3)));
    }
    // tau = 16th smallest of the 64 lane-minima via bitonic sort
    float taua, taub;
    {
        float va = mina, vb_ = minb;
#pragma unroll
        for (int k = 2; k <= 64; k <<= 1) {
#pragma unroll
            for (int j = k >> 1; j > 0; j >>= 1) {
                float oa = __shfl_xor(va, j, 64);
                float ob = __shfl_xor(vb_, j, 64);
                bool low = (lane & j) == 0;
                bool asc = (lane & k) == 0;
                va  = (low == asc) ? fminf(va, oa)  : fmaxf(va, oa);
                vb_ = (low == asc) ? fminf(vb_, ob) : fmaxf(vb_, ob);
            }
        }
        taua = __shfl(va, 15, 64);
        taub = __shfl(vb_, 15, 64);
    }
    int ca = 0, cb = 0;
    for (int m = lane; m < NPTS; m += 256) {
        float4 cc[4];
        cc[0] = pos4[base + m];
        cc[1] = pos4[base + m + 64];
        cc[2] = pos4[base + m + 128];
        cc[3] = pos4[base + m + 192];
#pragma unroll
        for (int u = 0; u < 4; u++) {
            float4 c = cc[u];
            int mm = m + u*64;
            float da = (pa.w + c.w) - 2.0f * fmaf(pa.z, c.z, fmaf(pa.y, c.y, pa.x*c.x));
            float db = (pb.w + c.w) - 2.0f * fmaf(pb.z, c.z, fmaf(pb.y, c.y, pb.x*c.x));
            bool ta = da <= taua, tb_ = db <= taub;
            unsigned long long ma = __ballot(ta), mb = __ballot(tb_);
            unsigned long long lower = (1ull << lane) - 1ull;
            if (ta) {
                int p_ = ca + __popcll(ma & lower);
                if (p_ < 256) { scd[w*2][p_] = da; sci[w*2][p_] = base + mm; }
            }
            if (tb_) {
                int p_ = cb + __popcll(mb & lower);
                if (p_ < 256) { scd[w*2+1][p_] = db; sci[w*2+1][p_] = base + mm; }
            }
            ca += __popcll(ma); cb += __popcll(mb);
        }
    }
    if (ca > 256) ca = 256;
    if (cb > 256) cb = 256;
    for (int i = ca + lane; i < 256; i += 64) { scd[w*2][i]   = FLT_MAX; sci[w*2][i]   = 0x7fffffff; }
    for (int i = cb + lane; i < 256; i += 64) { scd[w*2+1][i] = FLT_MAX; sci[w*2+1][i] = 0x7fffffff; }

    for (int pt = 0; pt < 2; pt++) {
        int s = w*2 + pt;
        float4 dv = *(const float4*)&scd[s][lane*4];
        int4   iv = *(const int4*)&sci[s][lane*4];
        CSW(dv.x, iv.x, dv.y, iv.y);
        CSW(dv.z, iv.z, dv.w, iv.w);
        CSW(dv.x, iv.x, dv.z, iv.z);
        CSW(dv.y, iv.y, dv.w, iv.w);
        CSW(dv.y, iv.y, dv.z, iv.z);
        int p = 0, myres = 0;
        for (int r = 0; r < 16; r++) {
            float hd = p==0 ? dv.x : p==1 ? dv.y : p==2 ? dv.z : p==3 ? dv.w : FLT_MAX;
            int   hi = p==0 ? iv.x : p==1 ? iv.y : p==2 ? iv.z : p==3 ? iv.w : 0x7fffffff;
            float bd = hd; int bi = hi;
            for (int off = 32; off; off >>= 1) {
                float od = __shfl_xor(bd, off, 64);
                int   oi = __shfl_xor(bi, off, 64);
                if (od < bd || (od == bd && oi < bi)) { bd = od; bi = oi; }
            }
            if (hi == bi) p++;
            if (lane == r) myres = bi;
        }
        if (lane < 16) knnb[(n0 + pt)*16 + lane] = myres;
    }
}

// ------------------------------------------------------------------ fused
// r8 structure EXACTLY (best measured: 114 us), plus a register-tier pin:
// an entry clobber of v64..v95 forces .vgpr_count >= 96, making the 8
// waves/EU tier (<=64 regs) impossible -- the allocator must settle at the
// 4 waves/EU tier (128-reg budget), which the ~100-reg live set fits with
// no spill.  LDS already caps residency at 16 waves/CU = 4 waves/EU, so
// zero occupancy is lost.  (r9/r10: no attribute form dislodged the 64-reg
// choice; both regressed.  This is the mechanical form of the same pin.)
__global__ __attribute__((amdgpu_waves_per_eu(4, 4)))
__launch_bounds__(1024) void fused_kernel(
    const float4* __restrict__ pos4, const int* __restrict__ knnb,
    const unsigned short* __restrict__ qb, const unsigned short* __restrict__ kb,
    const unsigned short* __restrict__ vb,
    const unsigned short* __restrict__ wB,
    const float* __restrict__ d1w, const float* __restrict__ d1b,
    const float* __restrict__ d2b, const float* __restrict__ g1b,
    const float* __restrict__ g2b,
    float* __restrict__ res, float* __restrict__ attn) {
    // force VGPR count past the 64-reg tier (nothing vector-live crosses
    // this point, so it costs zero instructions)
    asm volatile("" :::
        "v64","v65","v66","v67","v68","v69","v70","v71",
        "v72","v73","v74","v75","v76","v77","v78","v79",
        "v80","v81","v82","v83","v84","v85","v86","v87",
        "v88","v89","v90","v91","v92","v93","v94","v95");

    __shared__ unsigned short ws_[49152];   // 96 KB: d2 | g1 | g2 B-frags
    __shared__ unsigned short tb[16][2048]; // 4 KB/wave tile (64 KB)
    int t = threadIdx.x;
    int lane = t & 63, w = t >> 6;
    int col = lane & 15, quad = lane >> 4;
    const float inv_s = 0.08838834764831845f;   // 1/sqrt(128)

    unsigned short* tw = &tb[w][0];
    float* twf = (float*)tw;                    // tile viewed as f32 [16][64]

    // ---- load all three weight matrices, once
    {
        const uint4* src = (const uint4*)wB;
        uint4* dst = (uint4*)ws_;
        for (int i = t; i < 6144; i += 1024) dst[i] = src[i];
    }
    __syncthreads();   // the only barrier

#pragma unroll
    for (int it = 0; it < 2; it++) {
        int n = (blockIdx.x * 16 + w) * 2 + it;
        {
            int jid = knnb[n*16 + col];

            // ---- wide-gather k rows -> tile (swizzled 8-elem groups)
#pragma unroll
            for (int g = 0; g < 4; g++) {
                int kk2 = quad*4 + g;
                int jr2 = __shfl(jid, kk2);
                v8s kr = *(const v8s*)&kb[(size_t)jr2*128 + col*8];
                *(v8s*)&tw[kk2*128 + ((col ^ (kk2 & 7)) << 3)] = kr;
            }

            float4 pn = pos4[n];
            float4 pj = pos4[jid];
            float dx = pn.x - pj.x, dy = pn.y - pj.y, dz = pn.z - pj.z;

            // hd in A-frag layout (cvt_pk packs pairs)
            v8s af[4];
#pragma unroll
            for (int ks = 0; ks < 4; ks++) {
                int fb = ks*32 + quad*8;
                float w0[8], w1[8], w2[8], bb[8];
                *(float4*)&w0[0] = *(const float4*)&d1w[fb];
                *(float4*)&w0[4] = *(const float4*)&d1w[fb+4];
                *(float4*)&w1[0] = *(const float4*)&d1w[128+fb];
                *(float4*)&w1[4] = *(const float4*)&d1w[128+fb+4];
                *(float4*)&w2[0] = *(const float4*)&d1w[256+fb];
                *(float4*)&w2[4] = *(const float4*)&d1w[256+fb+4];
                *(float4*)&bb[0] = *(const float4*)&d1b[fb];
                *(float4*)&bb[4] = *(const float4*)&d1b[fb+4];
                union { v8s s; unsigned u[4]; } afu;
#pragma unroll
                for (int j2 = 0; j2 < 4; j2++) {
                    float h0 = fmaf(dz, w2[j2*2],   fmaf(dy, w1[j2*2],   fmaf(dx, w0[j2*2],   bb[j2*2])));
                    float h1 = fmaf(dz, w2[j2*2+1], fmaf(dy, w1[j2*2+1], fmaf(dx, w0[j2*2+1], bb[j2*2+1])));
                    afu.u[j2] = pack2(fmaxf(h0, 0.0f), fmaxf(h1, 0.0f));
                }
                af[ks] = afu.s;
            }

            v8s frag[4];
            unsigned peP[16];

            // ===== stage 1: pe = hd@d2; a = q - k + pe -> tile -> frag =====
            {
                unsigned wo = 0; asm volatile("" : "+v"(wo));
#pragma unroll
                for (int tt = 0; tt < 8; tt++) {
                    v4f acc = {0.f, 0.f, 0.f, 0.f};
#pragma unroll
                    for (int ks = 0; ks < 4; ks++) {
                        v8s b = *(const v8s*)&ws_[wo + ((tt*4 + ks) << 9) + (lane << 3)];
                        acc = __builtin_amdgcn_mfma_f32_16x16x32_bf16(af[ks], b, acc, 0, 0, 0);
                    }
                    int cg = tt*16 + col;
                    float bias = d2b[cg];
                    float qv = bf2f(qb[(size_t)n*128 + cg]);
                    float pe0 = 0.f, pe1 = 0.f;
#pragma unroll
                    for (int r = 0; r < 4; r++) {
                        int kk = quad*4 + r;
                        int pidx = kk*128 + ((((cg >> 3) ^ (kk & 7))) << 3) + (cg & 6);
                        unsigned kp = *(const unsigned*)&tw[pidx];
                        float kv = bf2f((unsigned short)((lane & 1) ? (kp >> 16) : (kp & 0xffff)));
                        float pe = acc[r] + bias;
                        if (r == 0) pe0 = pe;
                        if (r == 1) { peP[tt*2]   = pack2(pe0, pe); }
                        if (r == 2) pe1 = pe;
                        if (r == 3) { peP[tt*2+1] = pack2(pe1, pe); }
                        float a  = qv - kv + pe;
                        float o = __shfl_xor(a, 1);
                        if ((lane & 1) == 0) *(unsigned*)&tw[pidx] = pack2(a, o);
                    }
                }
#pragma unroll
                for (int ks = 0; ks < 4; ks++)
                    frag[ks] = *(const v8s*)&tw[col*128 + ((((ks*4 + quad) ^ (col & 7))) << 3)];
            }

            // ===== stage 2: gh = relu(a @ g1) -> tile -> frag ==============
            {
                unsigned wo = 16384; asm volatile("" : "+v"(wo));
#pragma unroll
                for (int tt = 0; tt < 8; tt++) {
                    v4f acc = {0.f, 0.f, 0.f, 0.f};
#pragma unroll
                    for (int ks = 0; ks < 4; ks++) {
                        v8s b = *(const v8s*)&ws_[wo + ((tt*4 + ks) << 9) + (lane << 3)];
                        acc = __builtin_amdgcn_mfma_f32_16x16x32_bf16(frag[ks], b, acc, 0, 0, 0);
                    }
                    float bias = g1b[tt*16 + col];
#pragma unroll
                    for (int r = 0; r < 4; r++) {
                        float h = fmaxf(acc[r] + bias, 0.0f);
                        float o = __shfl_xor(h, 1);
                        if ((lane & 1) == 0) {
                            int kk = quad*4 + r;
                            int cg = tt*16 + col;
                            int idx = kk*128 + ((((cg >> 3) ^ (kk & 7))) << 3) + (cg & 7);
                            *(unsigned*)&tw[idx] = pack2(h, o);
                        }
                    }
                }
#pragma unroll
                for (int ks = 0; ks < 4; ks++)
                    frag[ks] = *(const v8s*)&tw[col*128 + ((((ks*4 + quad) ^ (col & 7))) << 3)];
            }

            // ===== stage 3: gm = gh@g2 -> softmax -> attn, res =============
            {
                // gather v rows -> tile (gh already consumed into frag)
#pragma unroll
                for (int g = 0; g < 4; g++) {
                    int kk2 = quad*4 + g;
                    int jr2 = __shfl(jid, kk2);
                    v8s vr = *(const v8s*)&vb[(size_t)jr2*128 + col*8];
                    *(v8s*)&tw[kk2*128 + ((col ^ (kk2 & 7)) << 3)] = vr;
                }

                unsigned wo = 32768; asm volatile("" : "+v"(wo));
                float av[8][4];
#pragma unroll
                for (int tt = 0; tt < 8; tt++) {
                    v4f acc = {0.f, 0.f, 0.f, 0.f};
#pragma unroll
                    for (int ks = 0; ks < 4; ks++) {
                        v8s b = *(const v8s*)&ws_[wo + ((tt*4 + ks) << 9) + (lane << 3)];
                        acc = __builtin_amdgcn_mfma_f32_16x16x32_bf16(frag[ks], b, acc, 0, 0, 0);
                    }
                    int cg = tt*16 + col;
                    float bias = g2b[cg];
                    float l[4];
                    float mx = -FLT_MAX;
#pragma unroll
                    for (int r = 0; r < 4; r++) {
                        l[r] = (acc[r] + bias) * inv_s;
                        mx = fmaxf(mx, l[r]);
                    }
                    mx = fmaxf(mx, __shfl_xor(mx, 16));
                    mx = fmaxf(mx, __shfl_xor(mx, 32));
                    float s = 0.f;
#pragma unroll
                    for (int r = 0; r < 4; r++) { l[r] = __expf(l[r] - mx); s += l[r]; }
                    s += __shfl_xor(s, 16);
                    s += __shfl_xor(s, 32);
                    float rs = 1.0f / s;
                    float rp = 0.f;
#pragma unroll
                    for (int r = 0; r < 4; r++) {
                        int kk = quad*4 + r;
                        int pidx = kk*128 + ((((cg >> 3) ^ (kk & 7))) << 3) + (cg & 6);
                        unsigned vp = *(const unsigned*)&tw[pidx];
                        float vv = bf2f((unsigned short)((lane & 1) ? (vp >> 16) : (vp & 0xffff)));
                        unsigned pp = peP[tt*2 + (r >> 1)];
                        float pe = bf2f((unsigned short)((r & 1) ? (pp >> 16) : (pp & 0xffff)));
                        float a_ = l[r] * rs;
                        av[tt][r] = a_;
                        rp = fmaf(a_, vv + pe, rp);
                    }
                    rp += __shfl_xor(rp, 16);
                    rp += __shfl_xor(rp, 32);
                    if (lane < 16) res[(size_t)n*128 + cg] = rp;
                }

                // flush attn from av regs via the (now free) tile: two 4 KB
                // halves, 256B-contiguous float4 row stores
#pragma unroll
                for (int h = 0; h < 2; h++) {
#pragma unroll
                    for (int tt2 = 0; tt2 < 4; tt2++) {
#pragma unroll
                        for (int r = 0; r < 4; r++) {
                            int kk = quad*4 + r;
                            twf[kk*64 + ((tt2*16 + col) ^ ((kk & 4) << 2))] = av[h*4 + tt2][r];
                        }
                    }
#pragma unroll
                    for (int s4 = 0; s4 < 4; s4++) {
                        int kk = s4*4 + quad;
                        int c4 = col*4;
                        float4 a4 = *(const float4*)&twf[kk*64 + (c4 ^ ((kk & 4) << 2))];
                        *(float4*)&attn[(size_t)(n*16 + kk)*128 + h*64 + c4] = a4;
                    }
                }
            }
        }
    }
}

// ------------------------------------------------------------------ epi
__global__ __launch_bounds__(256) void epi_kernel(
    const float* __restrict__ res, const float* __restrict__ fc2w,
    const float* __restrict__ fc2b, const float* __restrict__ x,
    float* __restrict__ out) {
    __shared__ float fw[128][64];   // 32 KB
    __shared__ float rs[16][128];   // 8 KB
    int t = threadIdx.x;
    int rb = blockIdx.x * 16;
    for (int i = t; i < 8192; i += 256) fw[i >> 6][i & 63] = fc2w[i];
    for (int i = t; i < 2048; i += 256) rs[i >> 7][i & 127] = res[(size_t)rb*128 + i];
    __syncthreads();

    int o = t & 63, g = t >> 6;
#pragma unroll
    for (int rr = 0; rr < 4; rr++) {
        int lr = rr*4 + g;
        int n = rb + lr;
        float a0 = 0.f, a1 = 0.f, a2 = 0.f, a3 = 0.f;
#pragma unroll 8
        for (int c = 0; c < 128; c += 4) {
            a0 = fmaf(rs[lr][c],   fw[c][o],   a0);
            a1 = fmaf(rs[lr][c+1], fw[c+1][o], a1);
            a2 = fmaf(rs[lr][c+2], fw[c+2][o], a2);
            a3 = fmaf(rs[lr][c+3], fw[c+3][o], a3);
        }
        out[(size_t)n*64 + o] = (a0 + a1) + (a2 + a3) + fc2b[o] + x[(size_t)n*64 + o];
    }
}

// ------------------------------------------------------------------ launch
extern "C" void kernel_launch(void* const* d_in, const int* in_sizes, int n_in,
                              void* d_out, int out_size, void* d_ws, size_t ws_size,
                              hipStream_t stream) {
    (void)in_sizes; (void)n_in; (void)out_size; (void)ws_size;
    const float* x    = (const float*)d_in[0];
    const float* pos  = (const float*)d_in[1];
    const float* fc1w = (const float*)d_in[2];
    const float* fc1b = (const float*)d_in[3];
    const float* fc2w = (const float*)d_in[4];
    const float* fc2b = (const float*)d_in[5];
    const float* d1w  = (const float*)d_in[6];
    const float* d1b  = (const float*)d_in[7];
    const float* d2w  = (const float*)d_in[8];
    const float* d2b  = (const float*)d_in[9];
    const float* g1w  = (const float*)d_in[10];
    const float* g1b  = (const float*)d_in[11];
    const float* g2w  = (const float*)d_in[12];
    const float* g2b  = (const float*)d_in[13];
    const float* wq   = (const float*)d_in[14];
    const float* wk   = (const float*)d_in[15];
    const float* wv   = (const float*)d_in[16];

    float* out      = (float*)d_out;
    float* attn_out = out + (size_t)BN * DIN;

    char* W = (char*)d_ws;
    float4*         pos4  = (float4*)(W + 0);                 // 256 KB
    unsigned short* wB    = (unsigned short*)(W + 262144);    // 96 KB
    int*            knnb  = (int*)(W + 376832);               // 1 MB
    unsigned short* qb    = (unsigned short*)(W + 1441792);   // 4 MB
    unsigned short* kb    = (unsigned short*)(W + 5636096);   // 4 MB
    unsigned short* vb    = (unsigned short*)(W + 9830400);   // 4 MB
    float*          res   = (float*)(W + 14024704);           // 8 MB

    fp_kernel<<<1280, 256, 0, stream>>>(pos, x, fc1w, fc1b, wq, wk, wv,
                                        d2w, g1w, g2w, pos4, wB, qb, kb, vb);
    knn_kernel<<<2048, 256, 0, stream>>>(pos4, knnb);
    fused_kernel<<<512, 1024, 0, stream>>>(pos4, knnb, qb, kb, vb, wB, d1w, d1b,
                                           d2b, g1b, g2b, res, attn_out);
    epi_kernel<<<1024, 256, 0, stream>>>(res, fc2w, fc2b, x, out);
}